// Round 5
// baseline (49.132 us; speedup 1.0000x reference)
//
#include <hip/hip_runtime.h>
#include <math.h>

// Problem: B=256, D=512, H=512.
// Separable head: pre[i,j,h] = A'[j,h] + C[i,h]
//   A'[j,h] = emb[j,:] @ W1[0:512, h] + b1[h]
//   C [i,h] = emb[i,:] @ W1[512:1024, h]
// loss[i,j] = BCE(labels[i]==labels[j], sigmoid(sum_h relu(A'+C)*w2[h] + b2))
//
// Round-4: fix round-3's slab-stride bug (chunk stride was 2*B*H while each
// chunk held only B*H -> reducer mixed A'+C and summed poison). P layout is
// now compact [z][ks][row][h]; KS templated and picked from ws_size.

#define B 256
#define D 512
#define H 512
#define ROWS_H (B * H)   // floats per (z,ks) chunk: 131072 (= 0.5 MiB)

// ---------------- Kernel 1: partial GEMM -----------------------------------
// grid: (KS, 8 row-groups of 32, 2 z), 256 threads (4 waves).
// Wave w handles rows r0+8w..r0+8w+7, all 512 h (lane l owns h = k*64+l).
// One LDS e-read (float4) feeds 32 FMAs; W1 loads are coalesced 256B.
template <int KS>
__global__ __launch_bounds__(256) void head_partial(
    const float* __restrict__ emb, const float* __restrict__ W1,
    const float* __restrict__ b1, float* __restrict__ P) {
    constexpr int DC = D / KS;            // d-values per chunk
    __shared__ float sE[32 * DC];

    const int ks = blockIdx.x;
    const int r0 = blockIdx.y * 32;
    const int z  = blockIdx.z;
    const int d0 = ks * DC;

    // Stage 32 rows x DC d-values.
    constexpr int F4R = DC / 4;           // float4 per row
    for (int idx = threadIdx.x; idx < 32 * F4R; idx += 256) {
        const int r  = idx / F4R;
        const int c4 = idx % F4R;
        *(float4*)&sE[r * DC + c4 * 4] =
            *(const float4*)&emb[(size_t)(r0 + r) * D + d0 + c4 * 4];
    }
    __syncthreads();

    const int wave = threadIdx.x >> 6;
    const int lane = threadIdx.x & 63;

    float acc[8][8];   // [row][h-group]
    if (z == 0 && ks == 0) {
#pragma unroll
        for (int k = 0; k < 8; ++k) {
            const float bv = b1[k * 64 + lane];
#pragma unroll
            for (int r = 0; r < 8; ++r) acc[r][k] = bv;
        }
    } else {
#pragma unroll
        for (int r = 0; r < 8; ++r)
#pragma unroll
            for (int k = 0; k < 8; ++k) acc[r][k] = 0.0f;
    }

    const float* wp = W1 + (size_t)(z * D + d0) * H + lane;

    for (int d = 0; d < DC; d += 4) {
        float wv[4][8];
#pragma unroll
        for (int dd = 0; dd < 4; ++dd)
#pragma unroll
            for (int k = 0; k < 8; ++k)
                wv[dd][k] = wp[(size_t)(d + dd) * H + k * 64];  // coalesced 256B
#pragma unroll
        for (int r = 0; r < 8; ++r) {
            const float4 e = *(const float4*)&sE[(8 * wave + r) * DC + d];
#pragma unroll
            for (int k = 0; k < 8; ++k) {
                acc[r][k] = fmaf(e.x, wv[0][k], acc[r][k]);
                acc[r][k] = fmaf(e.y, wv[1][k], acc[r][k]);
                acc[r][k] = fmaf(e.z, wv[2][k], acc[r][k]);
                acc[r][k] = fmaf(e.w, wv[3][k], acc[r][k]);
            }
        }
    }

    // Compact chunk layout: P[(z*KS + ks) * ROWS_H + row*H + h]
    float* chunk = P + (size_t)(z * KS + ks) * ROWS_H;
#pragma unroll
    for (int r = 0; r < 8; ++r) {
        float* dst = chunk + (size_t)(r0 + 8 * wave + r) * H + lane;
#pragma unroll
        for (int k = 0; k < 8; ++k) dst[k * 64] = acc[r][k];
    }
}

// ---------------- Kernel 2: collapse KS partial chunks ---------------------
// AC[z][row][h] = sum_ks P[z][ks][row][h]. 256 blocks x 256 threads; one
// float4 per thread (65536 f4 = 2*B*H floats).
template <int KS>
__global__ __launch_bounds__(256) void reduce_partials(
    const float* __restrict__ P, float* __restrict__ AC) {
    const int g = blockIdx.x * 256 + threadIdx.x;   // 0..65535 (f4 index)
    const int zhalf = g >> 15;                      // 32768 f4 per z-half
    const int gi = g & 32767;
    const float4* base = (const float4*)P + (size_t)zhalf * KS * (ROWS_H / 4);

    float4 s = base[gi];
#pragma unroll
    for (int k = 1; k < KS; ++k) {
        float4 v = base[(size_t)k * (ROWS_H / 4) + gi];
        s.x += v.x; s.y += v.y; s.z += v.z; s.w += v.w;
    }
    ((float4*)AC)[g] = s;
}

// ---------------- Kernel 3: pairwise relu-dot + BCE ------------------------
// 16x16 pair tile, 128 threads, 2 outputs/thread (proven structure).
#define PADH 516  // row-start bank = 4*r mod 32 -> only 2-way aliasing (free)

__global__ __launch_bounds__(128) void pair_loss(
    const float* __restrict__ AC, const float* __restrict__ w2,
    const float* __restrict__ b2, const int* __restrict__ labels,
    float* __restrict__ out) {
    __shared__ float sA[16][PADH];
    __shared__ float sC[16][PADH];

    const float* Am = AC;                     // z=0 half: A' rows
    const float* Cm = AC + (size_t)ROWS_H;    // z=1 half: C rows

    const int j0 = blockIdx.x * 16;
    const int i0 = blockIdx.y * 16;
    const int tid = threadIdx.x;

    for (int idx = tid; idx < 16 * (H / 4); idx += 128) {
        const int r = idx >> 7;          // H/4 = 128 float4 per row
        const int c4 = idx & 127;
        float4 va = ((const float4*)(Am + (size_t)(j0 + r) * H))[c4];
        *(float4*)&sA[r][c4 * 4] = va;
        float4 vc = ((const float4*)(Cm + (size_t)(i0 + r) * H))[c4];
        *(float4*)&sC[r][c4 * 4] = vc;
    }
    __syncthreads();

    const int tx = tid & 15;   // j within tile
    const int ty = tid >> 4;   // i within tile: rows ty and ty+8

    float s0 = 0.0f, s1 = 0.0f;
#pragma unroll 4
    for (int h = 0; h < H; h += 4) {
        float4 a  = *(const float4*)&sA[tx][h];
        float4 c0 = *(const float4*)&sC[ty][h];
        float4 c1 = *(const float4*)&sC[ty + 8][h];
        float4 w  = *(const float4*)&w2[h];   // wave-uniform -> s_load
        s0 = fmaf(fmaxf(a.x + c0.x, 0.0f), w.x, s0);
        s0 = fmaf(fmaxf(a.y + c0.y, 0.0f), w.y, s0);
        s0 = fmaf(fmaxf(a.z + c0.z, 0.0f), w.z, s0);
        s0 = fmaf(fmaxf(a.w + c0.w, 0.0f), w.w, s0);
        s1 = fmaf(fmaxf(a.x + c1.x, 0.0f), w.x, s1);
        s1 = fmaf(fmaxf(a.y + c1.y, 0.0f), w.y, s1);
        s1 = fmaf(fmaxf(a.z + c1.z, 0.0f), w.z, s1);
        s1 = fmaf(fmaxf(a.w + c1.w, 0.0f), w.w, s1);
    }

    const float bias = b2[0];
    const int j = j0 + tx;
    const int lj = labels[j];

#pragma unroll
    for (int q = 0; q < 2; ++q) {
        const int i = i0 + ty + q * 8;
        const float z = (q ? s1 : s0) + bias;
        float p = 1.0f / (1.0f + expf(-z));
        p = fminf(fmaxf(p, 1e-7f), 1.0f - 1e-7f);
        const float t = (labels[i] == lj) ? 1.0f : 0.0f;
        const float loss = -(t * logf(p) + (1.0f - t) * log1pf(-p));
        out[(size_t)i * B + j] = loss;
    }
}

// ---------------- Host ------------------------------------------------------
template <int KS>
static void run_pipeline(const float* emb, const int* labels, const float* W1,
                         const float* b1, const float* W2, const float* b2,
                         float* out, float* ws, hipStream_t stream) {
    float* P  = ws;                                    // KS*2*ROWS_H floats
    float* AC = ws + (size_t)KS * 2 * ROWS_H;          // 2*ROWS_H floats

    dim3 g1(KS, 8, 2);
    head_partial<KS><<<g1, 256, 0, stream>>>(emb, W1, b1, P);
    reduce_partials<KS><<<256, 256, 0, stream>>>(P, AC);
    dim3 g2(16, 16);
    pair_loss<<<g2, 128, 0, stream>>>(AC, W2, b2, labels, out);
}

extern "C" void kernel_launch(void* const* d_in, const int* in_sizes, int n_in,
                              void* d_out, int out_size, void* d_ws, size_t ws_size,
                              hipStream_t stream) {
    const float* emb    = (const float*)d_in[0];
    const int*   labels = (const int*)d_in[1];
    const float* W1     = (const float*)d_in[2];
    const float* b1     = (const float*)d_in[3];
    const float* W2     = (const float*)d_in[4];
    const float* b2     = (const float*)d_in[5];
    float* out = (float*)d_out;
    float* ws  = (float*)d_ws;

    // Bytes needed for KS chunks + AC: (KS*2 + 2) * ROWS_H * 4.
    auto need = [](int ks) { return (size_t)(ks * 2 + 2) * ROWS_H * 4; };

    if (ws_size >= need(32))
        run_pipeline<32>(emb, labels, W1, b1, W2, b2, out, ws, stream);
    else if (ws_size >= need(16))
        run_pipeline<16>(emb, labels, W1, b1, W2, b2, out, ws, stream);
    else if (ws_size >= need(8))
        run_pipeline<8>(emb, labels, W1, b1, W2, b2, out, ws, stream);
    else
        run_pipeline<4>(emb, labels, W1, b1, W2, b2, out, ws, stream);
}

// Round 6
// 36.788 us; speedup vs baseline: 1.3355x; 1.3355x over previous
//
#include <hip/hip_runtime.h>
#include <math.h>

// Problem: B=256, D=512, H=512.
// Separable head: pre[i,j,h] = A'[j,h] + C[i,h]
//   A'[j,h] = emb[j,:] @ W1[0:512, h] + b1[h]
//   C [i,h] = emb[i,:] @ W1[512:1024, h]
// loss[i,j] = BCE(labels[i]==labels[j], sigmoid(sum_h relu(A'+C)*w2[h] + b2))
//
// Round-6: KS=4 (4 MiB partials, summed during pair_loss staging — no reduce
// kernel), head inner loop keeps 1-LDS-read:32-FMA ratio AND uses float4 W1
// loads (lane owns h = k*256 + 4*lane + e) to cut VMEM issue count 4x.
// Round-5 lesson: KS=32's 32 MiB partial round-trip + 3rd launch cost ~15us.

#define B 256
#define D 512
#define H 512
#define KS 4
#define DC (D / KS)       // 128 d-values per chunk
#define ROWS_H (B * H)    // floats per (z,ks) chunk

__device__ __forceinline__ float4 fma4(float s, float4 w, float4 a) {
    a.x = fmaf(s, w.x, a.x);
    a.y = fmaf(s, w.y, a.y);
    a.z = fmaf(s, w.z, a.z);
    a.w = fmaf(s, w.w, a.w);
    return a;
}

// ---------------- Kernel 1: partial GEMM -----------------------------------
// grid (KS, 32, 2) = 256 blocks, 256 threads (4 waves).
// Block: 8 rows x all 512 h x DC=128 d. Wave owns 2 rows; lane owns 8 h as
// two float4 groups (h = k*256 + 4*lane). One broadcast e-read feeds 32 FMAs.
__global__ __launch_bounds__(256) void head_partial(
    const float* __restrict__ emb, const float* __restrict__ W1,
    const float* __restrict__ b1, float* __restrict__ P) {
    __shared__ float sE[8 * DC];   // 8 rows x 128 d = 4 KiB

    const int ks = blockIdx.x;
    const int r0 = blockIdx.y * 8;
    const int z  = blockIdx.z;
    const int d0 = ks * DC;

    // Stage 8 rows x 128 d: one float4 per thread, coalesced.
    {
        const int r  = threadIdx.x >> 5;        // 0..7
        const int c4 = threadIdx.x & 31;        // 0..31
        *(float4*)&sE[r * DC + c4 * 4] =
            *(const float4*)&emb[(size_t)(r0 + r) * D + d0 + c4 * 4];
    }
    __syncthreads();

    const int wave = threadIdx.x >> 6;
    const int lane = threadIdx.x & 63;
    const int hb   = 4 * lane;                  // h-offset within a 256-group

    float4 acc[2][2];                           // [row][k]
    if (z == 0 && ks == 0) {
        const float4 b0 = *(const float4*)&b1[hb];
        const float4 bk = *(const float4*)&b1[256 + hb];
        acc[0][0] = b0; acc[1][0] = b0;
        acc[0][1] = bk; acc[1][1] = bk;
    } else {
        const float4 zf = make_float4(0.f, 0.f, 0.f, 0.f);
        acc[0][0] = zf; acc[0][1] = zf; acc[1][0] = zf; acc[1][1] = zf;
    }

    const float* wp = W1 + (size_t)(z * D + d0) * H + hb;
    const float* eb = sE + (2 * wave) * DC;     // this wave's 2 rows

#pragma unroll 2
    for (int d = 0; d < DC; d += 4) {
        float4 wv[4][2];
#pragma unroll
        for (int dd = 0; dd < 4; ++dd) {
            const float* wr = wp + (size_t)(d + dd) * H;
            wv[dd][0] = *(const float4*)wr;          // 1 KiB coalesced
            wv[dd][1] = *(const float4*)(wr + 256);
        }
#pragma unroll
        for (int r = 0; r < 2; ++r) {
            const float4 e = *(const float4*)&eb[r * DC + d];  // broadcast
            acc[r][0] = fma4(e.x, wv[0][0], acc[r][0]);
            acc[r][1] = fma4(e.x, wv[0][1], acc[r][1]);
            acc[r][0] = fma4(e.y, wv[1][0], acc[r][0]);
            acc[r][1] = fma4(e.y, wv[1][1], acc[r][1]);
            acc[r][0] = fma4(e.z, wv[2][0], acc[r][0]);
            acc[r][1] = fma4(e.z, wv[2][1], acc[r][1]);
            acc[r][0] = fma4(e.w, wv[3][0], acc[r][0]);
            acc[r][1] = fma4(e.w, wv[3][1], acc[r][1]);
        }
    }

    // Compact chunk layout: P[(z*KS + ks)*ROWS_H + row*H + h]
    float* chunk = P + (size_t)(z * KS + ks) * ROWS_H;
#pragma unroll
    for (int r = 0; r < 2; ++r) {
        float* dst = chunk + (size_t)(r0 + 2 * wave + r) * H + hb;
        *(float4*)&dst[0]   = acc[r][0];
        *(float4*)&dst[256] = acc[r][1];
    }
}

// ---------------- Kernel 2: partial-sum staging + pairwise relu-dot + BCE --
// 16x16 pair tile, 128 threads, 2 outputs/thread (proven structure). Staging
// sums the KS=4 partial chunks inline.
#define PADH 516  // row-start bank = 4*r mod 32 -> only 2-way aliasing (free)

__global__ __launch_bounds__(128) void pair_loss(
    const float* __restrict__ P, const float* __restrict__ w2,
    const float* __restrict__ b2, const int* __restrict__ labels,
    float* __restrict__ out) {
    __shared__ float sA[16][PADH];
    __shared__ float sC[16][PADH];

    const int j0 = blockIdx.x * 16;
    const int i0 = blockIdx.y * 16;
    const int tid = threadIdx.x;
    const size_t CSTR = (size_t)ROWS_H;            // floats per chunk

    for (int idx = tid; idx < 16 * (H / 4); idx += 128) {
        const int r = idx >> 7;          // H/4 = 128 float4 per row
        const int c4 = idx & 127;
        const float* pa = P + (size_t)(j0 + r) * H + c4 * 4;               // z=0
        const float* pc = P + KS * CSTR + (size_t)(i0 + r) * H + c4 * 4;   // z=1
        float4 a0 = *(const float4*)(pa);
        float4 a1 = *(const float4*)(pa + CSTR);
        float4 a2 = *(const float4*)(pa + 2 * CSTR);
        float4 a3 = *(const float4*)(pa + 3 * CSTR);
        float4 c0 = *(const float4*)(pc);
        float4 c1 = *(const float4*)(pc + CSTR);
        float4 c2 = *(const float4*)(pc + 2 * CSTR);
        float4 c3 = *(const float4*)(pc + 3 * CSTR);
        float4 va, vc;
        va.x = (a0.x + a1.x) + (a2.x + a3.x);
        va.y = (a0.y + a1.y) + (a2.y + a3.y);
        va.z = (a0.z + a1.z) + (a2.z + a3.z);
        va.w = (a0.w + a1.w) + (a2.w + a3.w);
        vc.x = (c0.x + c1.x) + (c2.x + c3.x);
        vc.y = (c0.y + c1.y) + (c2.y + c3.y);
        vc.z = (c0.z + c1.z) + (c2.z + c3.z);
        vc.w = (c0.w + c1.w) + (c2.w + c3.w);
        *(float4*)&sA[r][c4 * 4] = va;
        *(float4*)&sC[r][c4 * 4] = vc;
    }
    __syncthreads();

    const int tx = tid & 15;   // j within tile
    const int ty = tid >> 4;   // i within tile: rows ty and ty+8

    float s0 = 0.0f, s1 = 0.0f;
#pragma unroll 4
    for (int h = 0; h < H; h += 4) {
        float4 a  = *(const float4*)&sA[tx][h];
        float4 c0 = *(const float4*)&sC[ty][h];
        float4 c1 = *(const float4*)&sC[ty + 8][h];
        float4 w  = *(const float4*)&w2[h];   // wave-uniform -> s_load
        s0 = fmaf(fmaxf(a.x + c0.x, 0.0f), w.x, s0);
        s0 = fmaf(fmaxf(a.y + c0.y, 0.0f), w.y, s0);
        s0 = fmaf(fmaxf(a.z + c0.z, 0.0f), w.z, s0);
        s0 = fmaf(fmaxf(a.w + c0.w, 0.0f), w.w, s0);
        s1 = fmaf(fmaxf(a.x + c1.x, 0.0f), w.x, s1);
        s1 = fmaf(fmaxf(a.y + c1.y, 0.0f), w.y, s1);
        s1 = fmaf(fmaxf(a.z + c1.z, 0.0f), w.z, s1);
        s1 = fmaf(fmaxf(a.w + c1.w, 0.0f), w.w, s1);
    }

    const float bias = b2[0];
    const int j = j0 + tx;
    const int lj = labels[j];

#pragma unroll
    for (int q = 0; q < 2; ++q) {
        const int i = i0 + ty + q * 8;
        const float z = (q ? s1 : s0) + bias;
        float p = 1.0f / (1.0f + expf(-z));
        p = fminf(fmaxf(p, 1e-7f), 1.0f - 1e-7f);
        const float t = (labels[i] == lj) ? 1.0f : 0.0f;
        const float loss = -(t * logf(p) + (1.0f - t) * log1pf(-p));
        out[(size_t)i * B + j] = loss;
    }
}

extern "C" void kernel_launch(void* const* d_in, const int* in_sizes, int n_in,
                              void* d_out, int out_size, void* d_ws, size_t ws_size,
                              hipStream_t stream) {
    const float* emb    = (const float*)d_in[0];
    const int*   labels = (const int*)d_in[1];
    const float* W1     = (const float*)d_in[2];
    const float* b1     = (const float*)d_in[3];
    const float* W2     = (const float*)d_in[4];
    const float* b2     = (const float*)d_in[5];
    float* out = (float*)d_out;

    float* P = (float*)d_ws;   // 2*KS*ROWS_H floats = 4 MiB of partials

    dim3 g1(KS, 32, 2);
    head_partial<<<g1, 256, 0, stream>>>(emb, W1, b1, P);

    dim3 g2(16, 16);
    pair_loss<<<g2, 128, 0, stream>>>(P, W2, b2, labels, out);
}

// Round 7
// 36.711 us; speedup vs baseline: 1.3383x; 1.0021x over previous
//
#include <hip/hip_runtime.h>
#include <math.h>

// Problem: B=256, D=512, H=512.
// Separable head: pre[i,j,h] = A'[j,h] + C[i,h]
//   A'[j,h] = emb[j,:] @ W1[0:512, h] + b1[h]
//   C [i,h] = emb[i,:] @ W1[512:1024, h]
// loss[i,j] = BCE(labels[i]==labels[j], sigmoid(sum_h relu(A'+C)*w2[h] + b2))
//
// Round-7: head is latency-bound on cold (fill-flushed) caches with too few
// waves (r6: 256 blocks, VALUBusy 4%). Now 1024 blocks (16 waves/CU), each
// wave's W1 footprint (16 float4) loaded in one upfront burst, cross-wave
// d-reduction in LDS. Reduce kernel (r4-proven) collapses KS=8 partials so
// pair staging reads AC once, not KS chunks per tile.

#define B 256
#define D 512
#define H 512
#define KS 8
#define DC (D / KS)       // 64 d per ks-chunk
#define ROWS_H (B * H)    // floats per (z,ks) chunk

__device__ __forceinline__ float4 fma4(float s, float4 w, float4 a) {
    a.x = fmaf(s, w.x, a.x);
    a.y = fmaf(s, w.y, a.y);
    a.z = fmaf(s, w.z, a.z);
    a.w = fmaf(s, w.w, a.w);
    return a;
}
__device__ __forceinline__ float4 add4(float4 a, float4 b) {
    a.x += b.x; a.y += b.y; a.z += b.z; a.w += b.w; return a;
}

// ---------------- Kernel 1: partial GEMM -----------------------------------
// grid (KS, 32, 4) = 1024 blocks, 256 thr (4 waves). Block: 8 rows x 256 h
// (h-half hs) x 64 d (chunk ks) for matrix z. Wave owns a 16-d quarter, all
// 8 rows, lane owns h-float4 (h0 + 4*lane). W1 (16 f4/thread) loaded in one
// burst; e broadcast from LDS (1 b128 read : 16 FMA); cross-wave d-sum via
// 32 KB LDS; coalesced f4 partial write.
__global__ __launch_bounds__(256, 4) void head_partial(
    const float* __restrict__ emb, const float* __restrict__ W1,
    float* __restrict__ P) {
    __shared__ float sE[8 * DC];            // 2 KB: 8 rows x 64 d
    __shared__ float4 part[4][8][64];       // 32 KB: [wave][row][lane]

    const int ks = blockIdx.x;
    const int r0 = blockIdx.y * 8;
    const int z  = blockIdx.z >> 1;
    const int hs = blockIdx.z & 1;
    const int d0 = ks * DC;
    const int h0 = hs * 256;

    // Stage 8 rows x 64 d (threads 0..127, one float4 each).
    if (threadIdx.x < 128) {
        const int r  = threadIdx.x >> 4;      // 0..7
        const int c4 = threadIdx.x & 15;      // 0..15
        *(float4*)&sE[r * DC + c4 * 4] =
            *(const float4*)&emb[(size_t)(r0 + r) * D + d0 + c4 * 4];
    }
    __syncthreads();

    const int w = threadIdx.x >> 6;
    const int l = threadIdx.x & 63;
    const int dq = w * 16;                    // this wave's d-quarter

    // Upfront W1 burst: 16 float4 (64 VGPR), all independent addresses.
    const float* wp = W1 + (size_t)(z * D + d0 + dq) * H + h0 + 4 * l;
    float4 wv[16];
#pragma unroll
    for (int dd = 0; dd < 16; ++dd)
        wv[dd] = *(const float4*)(wp + (size_t)dd * H);

    float4 acc[8];
#pragma unroll
    for (int r = 0; r < 8; ++r) acc[r] = make_float4(0.f, 0.f, 0.f, 0.f);

#pragma unroll
    for (int r = 0; r < 8; ++r) {
        const float* er = sE + r * DC + dq;
#pragma unroll
        for (int d4 = 0; d4 < 4; ++d4) {
            const float4 e = *(const float4*)&er[d4 * 4];   // broadcast b128
            acc[r] = fma4(e.x, wv[d4 * 4 + 0], acc[r]);
            acc[r] = fma4(e.y, wv[d4 * 4 + 1], acc[r]);
            acc[r] = fma4(e.z, wv[d4 * 4 + 2], acc[r]);
            acc[r] = fma4(e.w, wv[d4 * 4 + 3], acc[r]);
        }
    }

    // Cross-wave d-reduction: wave w posts its 8 row-partials.
#pragma unroll
    for (int r = 0; r < 8; ++r) part[w][r][l] = acc[r];
    __syncthreads();

    // Thread (w,l) combines rows 2w, 2w+1 across the 4 wave-partials.
    float* chunk = P + (size_t)(z * KS + ks) * ROWS_H;
#pragma unroll
    for (int q = 0; q < 2; ++q) {
        const int rr = 2 * w + q;
        float4 s = add4(add4(part[0][rr][l], part[1][rr][l]),
                        add4(part[2][rr][l], part[3][rr][l]));
        *(float4*)&chunk[(size_t)(r0 + rr) * H + h0 + 4 * l] = s;
    }
}

// ---------------- Kernel 2: collapse KS partial chunks (+b1 on A') ---------
// AC[z][row][h] = sum_ks P[z][ks][row][h] (+ b1[h] for z=0).
// 256 blocks x 256 threads, one float4 per thread.
__global__ __launch_bounds__(256) void reduce_partials(
    const float* __restrict__ P, const float* __restrict__ b1,
    float* __restrict__ AC) {
    const int g = blockIdx.x * 256 + threadIdx.x;   // 0..65535 (f4 index)
    const int zhalf = g >> 15;                      // 32768 f4 per z-half
    const int gi = g & 32767;
    const float4* base = (const float4*)P + (size_t)zhalf * KS * (ROWS_H / 4);

    float4 s = base[gi];
#pragma unroll
    for (int k = 1; k < KS; ++k)
        s = add4(s, base[(size_t)k * (ROWS_H / 4) + gi]);
    if (zhalf == 0)
        s = add4(s, ((const float4*)b1)[gi & 127]);   // h-f4 within row
    ((float4*)AC)[g] = s;
}

// ---------------- Kernel 3: pairwise relu-dot + BCE ------------------------
// 16x16 pair tile, 128 threads, 2 outputs/thread (proven structure).
#define PADH 516  // row-start bank = 4*r mod 32 -> only 2-way aliasing (free)

__global__ __launch_bounds__(128) void pair_loss(
    const float* __restrict__ AC, const float* __restrict__ w2,
    const float* __restrict__ b2, const int* __restrict__ labels,
    float* __restrict__ out) {
    __shared__ float sA[16][PADH];
    __shared__ float sC[16][PADH];

    const float* Am = AC;                     // z=0 half: A' rows
    const float* Cm = AC + (size_t)ROWS_H;    // z=1 half: C rows

    const int j0 = blockIdx.x * 16;
    const int i0 = blockIdx.y * 16;
    const int tid = threadIdx.x;

    for (int idx = tid; idx < 16 * (H / 4); idx += 128) {
        const int r = idx >> 7;          // H/4 = 128 float4 per row
        const int c4 = idx & 127;
        float4 va = ((const float4*)(Am + (size_t)(j0 + r) * H))[c4];
        *(float4*)&sA[r][c4 * 4] = va;
        float4 vc = ((const float4*)(Cm + (size_t)(i0 + r) * H))[c4];
        *(float4*)&sC[r][c4 * 4] = vc;
    }
    __syncthreads();

    const int tx = tid & 15;   // j within tile
    const int ty = tid >> 4;   // i within tile: rows ty and ty+8

    float s0 = 0.0f, s1 = 0.0f;
#pragma unroll 4
    for (int h = 0; h < H; h += 4) {
        float4 a  = *(const float4*)&sA[tx][h];
        float4 c0 = *(const float4*)&sC[ty][h];
        float4 c1 = *(const float4*)&sC[ty + 8][h];
        float4 w  = *(const float4*)&w2[h];   // wave-uniform -> s_load
        s0 = fmaf(fmaxf(a.x + c0.x, 0.0f), w.x, s0);
        s0 = fmaf(fmaxf(a.y + c0.y, 0.0f), w.y, s0);
        s0 = fmaf(fmaxf(a.z + c0.z, 0.0f), w.z, s0);
        s0 = fmaf(fmaxf(a.w + c0.w, 0.0f), w.w, s0);
        s1 = fmaf(fmaxf(a.x + c1.x, 0.0f), w.x, s1);
        s1 = fmaf(fmaxf(a.y + c1.y, 0.0f), w.y, s1);
        s1 = fmaf(fmaxf(a.z + c1.z, 0.0f), w.z, s1);
        s1 = fmaf(fmaxf(a.w + c1.w, 0.0f), w.w, s1);
    }

    const float bias = b2[0];
    const int j = j0 + tx;
    const int lj = labels[j];

#pragma unroll
    for (int q = 0; q < 2; ++q) {
        const int i = i0 + ty + q * 8;
        const float z = (q ? s1 : s0) + bias;
        float p = 1.0f / (1.0f + expf(-z));
        p = fminf(fmaxf(p, 1e-7f), 1.0f - 1e-7f);
        const float t = (labels[i] == lj) ? 1.0f : 0.0f;
        const float loss = -(t * logf(p) + (1.0f - t) * log1pf(-p));
        out[(size_t)i * B + j] = loss;
    }
}

extern "C" void kernel_launch(void* const* d_in, const int* in_sizes, int n_in,
                              void* d_out, int out_size, void* d_ws, size_t ws_size,
                              hipStream_t stream) {
    const float* emb    = (const float*)d_in[0];
    const int*   labels = (const int*)d_in[1];
    const float* W1     = (const float*)d_in[2];
    const float* b1     = (const float*)d_in[3];
    const float* W2     = (const float*)d_in[4];
    const float* b2     = (const float*)d_in[5];
    float* out = (float*)d_out;

    float* P  = (float*)d_ws;                    // 2*KS*ROWS_H f32 = 8 MiB
    float* AC = P + (size_t)2 * KS * ROWS_H;     // 2*ROWS_H f32 = 1 MiB

    dim3 g1(KS, 32, 4);
    head_partial<<<g1, 256, 0, stream>>>(emb, W1, P);

    reduce_partials<<<256, 256, 0, stream>>>(P, b1, AC);

    dim3 g2(16, 16);
    pair_loss<<<g2, 128, 0, stream>>>(AC, W2, b2, labels, out);
}